// Round 6
// baseline (170.359 us; speedup 1.0000x reference)
//
#include <hip/hip_runtime.h>
#include <hip/hip_fp16.h>

#define Mpts 32768
#define Vv 9
#define Cc 24
#define Hh 120
#define Ww 160
#define Npts (Mpts * 8)          // 262144
#define PIX (Hh * Ww)            // 19200
#define VOXEL 0.04f

#define NB_TF   (Vv * 300)       // 2700 tf-convert blocks
#define NB_GEMM (Mpts / 256)     // 128 pre_h gemm blocks
#define NB_Z    (Npts / 256)     // 1024 z-stat blocks (and main blocks)

// ---------------- workspace layout (bytes) ----------------
// OFF_RED  : red[NB_Z][3] doubles — per-block z partials      : 24576 B
// OFF_TICK : ticket counter (zeroed by hipMemsetAsync)        : 64 B
// OFF_ZST  : {zmean, izn} floats (written by last z-block)
// OFF_TF16 : ch0-15  fp8, 16B/pixel (V,H,W)                   : 2764800 B
// OFF_TF8  : ch16-23 fp8,  8B/pixel (V,H,W)                   : 1382400 B
// OFF_PREH : pre_h (M,24) f32                                 : 3145728 B
// total tf footprint 4.15 MB < 4 MiB+slack per-XCD L2 target.
#define OFF_RED   0
#define OFF_TICK  24576
#define OFF_ZST   24640
#define OFF_TF16  32768
#define OFF_TF8   (OFF_TF16 + Vv * PIX * 16)
#define OFF_PREH  (OFF_TF8 + Vv * PIX * 8)

typedef __attribute__((ext_vector_type(2))) float f32x2;
typedef __attribute__((ext_vector_type(4))) float f32x4;
typedef __attribute__((ext_vector_type(4))) int i32x4;

// 16B load with only 8B alignment guarantee (tf8 corner-pair tails).
// Backend emits dwordx4 @align8 if supported, else splits to 2x dwordx2 —
// never worse than the two separate loads it replaces.
__device__ __forceinline__ uint4 ld_u4_a8(const void* p) {
  struct __attribute__((packed, aligned(8))) A8 { uint4 v; };
  return ((const A8*)p)->v;
}

// pack 4 floats -> 4 fp8 e4m3 in one uint
__device__ __forceinline__ unsigned pack4fp8(float a, float b, float c,
                                             float d) {
  int u = __builtin_amdgcn_cvt_pk_fp8_f32(a, b, 0, false);
  u = __builtin_amdgcn_cvt_pk_fp8_f32(c, d, u, true);
  return (unsigned)u;
}

// ---------------- 1) prep: tf-convert | pre_h gemm | z-stats ---------------
__global__ __launch_bounds__(256) void prep_kernel(
    const float* __restrict__ feats, const float* __restrict__ pre_feat,
    const float* __restrict__ W_sp, const float* __restrict__ b_sp,
    const int* __restrict__ pre_coords, const float* __restrict__ KRcam,
    const float* __restrict__ vol_origin, uint4* __restrict__ tf16,
    uint2* __restrict__ tf8, float* __restrict__ pre_h,
    double* __restrict__ red, int* __restrict__ tick,
    float* __restrict__ zst) {
  __shared__ float tile[64][Cc + 1];   // tf path (6.4 KB)
  __shared__ float Wl[50 * Cc];        // gemm path (4.8 KB)
  __shared__ float bl[Cc];
  __shared__ float KRs[Vv * 12];       // z path
  __shared__ float origs[3];
  __shared__ float redl[3][4];
  __shared__ double dredl[3][4];
  __shared__ int s_last;
  int blk = blockIdx.x;

  if (blk < NB_TF) {
    // ---- feats(f32, C-major) -> tf16/tf8 (fp8, pixel-major) ----
    int v = blk / 300;
    int p0 = (blk % 300) * 64;
    const float* src = feats + (size_t)v * (Cc * PIX);
    for (int i = threadIdx.x; i < Cc * 64; i += 256) {
      int c = i >> 6, p = i & 63;
      tile[p][c] = __builtin_nontemporal_load(src + c * PIX + p0 + p);
    }
    __syncthreads();
    if (threadIdx.x < 64) {
      int p = threadIdx.x;
      const float* t = &tile[p][0];
      uint4 u;
      u.x = pack4fp8(t[0], t[1], t[2], t[3]);
      u.y = pack4fp8(t[4], t[5], t[6], t[7]);
      u.z = pack4fp8(t[8], t[9], t[10], t[11]);
      u.w = pack4fp8(t[12], t[13], t[14], t[15]);
      tf16[(size_t)v * PIX + p0 + p] = u;
    } else if (threadIdx.x < 128) {
      int p = threadIdx.x - 64;
      const float* t = &tile[p][0];
      uint2 u;
      u.x = pack4fp8(t[16], t[17], t[18], t[19]);
      u.y = pack4fp8(t[20], t[21], t[22], t[23]);
      tf8[(size_t)v * PIX + p0 + p] = u;
    }
  } else if (blk < NB_TF + NB_GEMM) {
    // ---- pre_h = pre_feat @ W_sp[25:75] + b ----
    int mb = blk - NB_TF;
    for (int i = threadIdx.x; i < 50 * Cc; i += 256) Wl[i] = W_sp[25 * Cc + i];
    if (threadIdx.x < Cc) bl[threadIdx.x] = b_sp[threadIdx.x];
    __syncthreads();
    int m = mb * 256 + threadIdx.x;
    float acc[Cc];
#pragma unroll
    for (int j = 0; j < Cc; j++) acc[j] = bl[j];
    const f32x2* pf = (const f32x2*)(pre_feat + (size_t)m * 50);
#pragma unroll 5
    for (int k = 0; k < 25; k++) {
      f32x2 x = __builtin_nontemporal_load(pf + k);
#pragma unroll
      for (int j = 0; j < Cc; j++)
        acc[j] += x.x * Wl[(2 * k) * Cc + j] + x.y * Wl[(2 * k + 1) * Cc + j];
    }
    f32x4* o4 = (f32x4*)(pre_h + (size_t)m * Cc);
#pragma unroll
    for (int t = 0; t < 6; t++) {
      f32x4 v4 = {acc[4 * t], acc[4 * t + 1], acc[4 * t + 2], acc[4 * t + 3]};
      o4[t] = v4;
    }
  } else {
    // ---- z-stat pass: projections only; last block finalizes zmean/izn ----
    int zblk = blk - (NB_TF + NB_GEMM);
    for (int i = threadIdx.x; i < Vv * 12; i += 256) {
      int v = i / 12, r = i - v * 12;
      KRs[i] = KRcam[v * 16 + r];
    }
    if (threadIdx.x < 3) origs[threadIdx.x] = vol_origin[threadIdx.x];
    __syncthreads();
    int n = zblk * 256 + threadIdx.x;
    int m = n >> 3, o = n & 7;
    i32x4 pc = __builtin_nontemporal_load((const i32x4*)pre_coords + m);
    int cx = pc.y + ((0xB2 >> o) & 1);
    int cy = pc.z + ((0xD4 >> o) & 1);
    int cz = pc.w + ((0xE8 >> o) & 1);
    float wx0 = (float)cx * VOXEL + origs[0];
    float wy0 = (float)cy * VOXEL + origs[1];
    float wz0 = (float)cz * VOXEL + origs[2];
    float zsum = 0.f;
    int cnt = 0;
    for (int v = 0; v < Vv; v++) {
      const float* kr = &KRs[v * 12];
      float ix = kr[0] * wx0 + kr[1] * wy0 + kr[2] * wz0 + kr[3];
      float iy = kr[4] * wx0 + kr[5] * wy0 + kr[6] * wz0 + kr[7];
      float iz = kr[8] * wx0 + kr[9] * wy0 + kr[10] * wz0 + kr[11];
      float sz = (fabsf(iz) > 1e-9f) ? iz : 1e-9f;
      float px = ix / sz;
      float py = iy / sz;
      bool msk = (px >= 0.f) && (px <= (float)(Ww - 1)) && (py >= 0.f) &&
                 (py <= (float)(Hh - 1)) && (iz > 0.f);
      if (msk) {
        zsum += iz;
        cnt++;
      }
    }
    float denom = fmaxf((float)cnt, 1.f);
    float z = zsum / denom;
    float rz = (z > 0.f) ? z : 0.f;
    float rz2 = rz * rz;
    float rcn = (z > 0.f) ? 1.f : 0.f;
#pragma unroll
    for (int off = 32; off > 0; off >>= 1) {
      rz += __shfl_down(rz, off);
      rz2 += __shfl_down(rz2, off);
      rcn += __shfl_down(rcn, off);
    }
    int wid = threadIdx.x >> 6, lid = threadIdx.x & 63;
    if (lid == 0) {
      redl[0][wid] = rz;
      redl[1][wid] = rz2;
      redl[2][wid] = rcn;
    }
    __syncthreads();
    if (threadIdx.x == 0) {
      float a = 0.f, b = 0.f, c = 0.f;
#pragma unroll
      for (int w = 0; w < 4; w++) {
        a += redl[0][w];
        b += redl[1][w];
        c += redl[2][w];
      }
      double* r3 = red + (size_t)zblk * 3;
      r3[0] = (double)a;
      r3[1] = (double)b;
      r3[2] = (double)c;
      __threadfence();                       // release slot
      int t = atomicAdd(tick, 1);            // device-scope
      s_last = (t == NB_Z - 1) ? 1 : 0;
    }
    __syncthreads();
    if (s_last) {
      __threadfence();                       // acquire all slots
      double a = 0.0, b = 0.0, c = 0.0;
      for (int s = threadIdx.x; s < NB_Z; s += 256) {
        const double* r3 = red + (size_t)s * 3;
        a += r3[0];
        b += r3[1];
        c += r3[2];
      }
#pragma unroll
      for (int off = 32; off > 0; off >>= 1) {
        a += __shfl_down(a, off);
        b += __shfl_down(b, off);
        c += __shfl_down(c, off);
      }
      if (lid == 0) {
        dredl[0][wid] = a;
        dredl[1][wid] = b;
        dredl[2][wid] = c;
      }
      __syncthreads();
      if (threadIdx.x == 0) {
        double A = 0.0, B = 0.0, C = 0.0;
#pragma unroll
        for (int w = 0; w < 4; w++) {
          A += dredl[0][w];
          B += dredl[1][w];
          C += dredl[2][w];
        }
        double npos = (C > 0.0) ? C : 1.0;
        double zmean = A / npos;
        double var = B - 2.0 * zmean * A + C * zmean * zmean;
        if (var < 0.0) var = 0.0;
        double znorm = sqrt(var) + 1e-5;
        zst[0] = (float)zmean;
        zst[1] = (float)(1.0 / znorm);
      }
    }
  }
}

// acc[0..15] += w * fp8x16(A)
__device__ __forceinline__ void acc16(uint4 A, float w, float* acc) {
#pragma unroll
  for (int t = 0; t < 4; t++) {
    unsigned u = ((const unsigned*)&A)[t];
    f32x2 f0 = __builtin_amdgcn_cvt_pk_f32_fp8((int)u, false);
    f32x2 f1 = __builtin_amdgcn_cvt_pk_f32_fp8((int)u, true);
    acc[4 * t + 0] += w * f0.x;
    acc[4 * t + 1] += w * f0.y;
    acc[4 * t + 2] += w * f1.x;
    acc[4 * t + 3] += w * f1.y;
  }
}
// acc[0..7] += w * fp8x8(ux,uy)
__device__ __forceinline__ void acc8v(unsigned ux, unsigned uy, float w,
                                      float* acc) {
  f32x2 f0 = __builtin_amdgcn_cvt_pk_f32_fp8((int)ux, false);
  f32x2 f1 = __builtin_amdgcn_cvt_pk_f32_fp8((int)ux, true);
  f32x2 f2 = __builtin_amdgcn_cvt_pk_f32_fp8((int)uy, false);
  f32x2 f3 = __builtin_amdgcn_cvt_pk_f32_fp8((int)uy, true);
  acc[0] += w * f0.x;
  acc[1] += w * f0.y;
  acc[2] += w * f1.x;
  acc[3] += w * f1.y;
  acc[4] += w * f2.x;
  acc[5] += w * f2.y;
  acc[6] += w * f3.x;
  acc[7] += w * f3.y;
}

// ---------------- 2) main: gather (split tf, 6 loads/view) + fused heads ---
__global__ __launch_bounds__(256) void main_kernel(
    const int* __restrict__ pre_coords, const uint4* __restrict__ tf16,
    const unsigned char* __restrict__ tf8, const float* __restrict__ KRcam,
    const float* __restrict__ vol_origin, const float* __restrict__ w2ac,
    const float* __restrict__ W_sp, const float* __restrict__ W_t,
    const float* __restrict__ b_t, const float* __restrict__ W_o,
    const float* __restrict__ b_o, const float* __restrict__ pre_h,
    float* __restrict__ out, const float* __restrict__ zst) {
  __shared__ float KR[Vv * 12];
  __shared__ float w2a[12];
  __shared__ float orig[3];
  for (int i = threadIdx.x; i < Vv * 12; i += 256) {
    int v = i / 12, r = i - v * 12;
    KR[i] = KRcam[v * 16 + r];
  }
  if (threadIdx.x < 12) w2a[threadIdx.x] = w2ac[threadIdx.x];
  if (threadIdx.x < 3) orig[threadIdx.x] = vol_origin[threadIdx.x];
  __syncthreads();

  float s_zmean = zst[0];   // uniform address -> scalar load
  float s_izn = zst[1];

  int n = blockIdx.x * 256 + threadIdx.x;
  int m = n >> 3, o = n & 7;
  i32x4 pc = __builtin_nontemporal_load((const i32x4*)pre_coords + m);
  int cx = pc.y + ((0xB2 >> o) & 1);
  int cy = pc.z + ((0xD4 >> o) & 1);
  int cz = pc.w + ((0xE8 >> o) & 1);
  float wx0 = (float)cx * VOXEL + orig[0];
  float wy0 = (float)cy * VOXEL + orig[1];
  float wz0 = (float)cz * VOXEL + orig[2];

  {  // r_coords
    float camx = w2a[0] * wx0 + w2a[1] * wy0 + w2a[2] * wz0 + w2a[3];
    float camy = w2a[4] * wx0 + w2a[5] * wy0 + w2a[6] * wz0 + w2a[7];
    float camz = w2a[8] * wx0 + w2a[9] * wy0 + w2a[10] * wz0 + w2a[11];
    f32x4 rc = {camx, camy, camz, (float)pc.x};
    __builtin_nontemporal_store(rc, (f32x4*)(out + 3 * (size_t)Npts) + n);
  }

  float acc[Cc];
#pragma unroll
  for (int c = 0; c < Cc; c++) acc[c] = 0.f;
  float zsum = 0.f;
  int cnt = 0;

  for (int v = 0; v < Vv; v++) {
    const float* kr = &KR[v * 12];
    float ix = kr[0] * wx0 + kr[1] * wy0 + kr[2] * wz0 + kr[3];
    float iy = kr[4] * wx0 + kr[5] * wy0 + kr[6] * wz0 + kr[7];
    float iz = kr[8] * wx0 + kr[9] * wy0 + kr[10] * wz0 + kr[11];
    float sz = (fabsf(iz) > 1e-9f) ? iz : 1e-9f;
    float px = ix / sz;
    float py = iy / sz;
    bool msk = (px >= 0.f) && (px <= (float)(Ww - 1)) && (py >= 0.f) &&
               (py <= (float)(Hh - 1)) && (iz > 0.f);
    if (msk) {
      int x0 = (int)floorf(px), y0 = (int)floorf(py);
      int xs = min(x0, Ww - 2), ys = min(y0, Hh - 2);
      float wx = px - (float)xs, wy = py - (float)ys;
      float w00 = (1.f - wx) * (1.f - wy);
      float w10 = wx * (1.f - wy);
      float w01 = (1.f - wx) * wy;
      float w11 = wx * wy;
      size_t pp = (size_t)(v * PIX + ys * Ww + xs);
      const uint4* h16 = tf16 + pp;
      uint4 A = h16[0], B = h16[1];          // row ys, px xs/xs+1, ch0-15
      uint4 C = h16[Ww], D = h16[Ww + 1];    // row ys+1
      const unsigned char* t8 = tf8 + pp * 8;
      uint4 Tab = ld_u4_a8(t8);              // row ys: both tails in 16B
      uint4 Tcd = ld_u4_a8(t8 + Ww * 8);     // row ys+1
      acc16(A, w00, &acc[0]);
      acc16(B, w10, &acc[0]);
      acc16(C, w01, &acc[0]);
      acc16(D, w11, &acc[0]);
      acc8v(Tab.x, Tab.y, w00, &acc[16]);
      acc8v(Tab.z, Tab.w, w10, &acc[16]);
      acc8v(Tcd.x, Tcd.y, w01, &acc[16]);
      acc8v(Tcd.z, Tcd.w, w11, &acc[16]);
      zsum += iz;
      cnt++;
    }
  }

  float denom = fmaxf((float)cnt, 1.f);
  float invd = 1.f / denom;
  float z = zsum * invd;

  // h = pre_h[m] + (acc*invd) @ W_sp[0:24,:]  (W_sp: uniform scalar loads)
  float h[Cc];
  {
    const f32x4* ph4 = (const f32x4*)(pre_h + (size_t)m * Cc);
#pragma unroll
    for (int t = 0; t < 6; t++) {
      f32x4 v4 = ph4[t];
      h[4 * t + 0] = v4.x;
      h[4 * t + 1] = v4.y;
      h[4 * t + 2] = v4.z;
      h[4 * t + 3] = v4.w;
    }
  }
#pragma unroll
  for (int c = 0; c < Cc; c++) {
    float f = acc[c] * invd;
#pragma unroll
    for (int j = 0; j < Cc; j++) h[j] += f * W_sp[c * Cc + j];
  }

  // ---- fused finalize: zn channel + relu + heads, h never leaves regs ----
  float zn = (z > 0.f) ? (z - s_zmean) * s_izn : 0.f;
  float tsdf = b_t[0], occ = b_o[0];
#pragma unroll
  for (int j = 0; j < Cc; j++) {
    float hj = fmaxf(h[j] + zn * W_sp[24 * Cc + j], 0.f);
    tsdf += hj * W_t[j];
    occ += hj * W_o[j];
  }
  f32x2 o2 = {tsdf, occ};
  __builtin_nontemporal_store(o2, (f32x2*)out + n);
  __builtin_nontemporal_store((float)cnt, out + 2 * (size_t)Npts + n);
}

// ---------------- launch ---------------------------------------------------
extern "C" void kernel_launch(void* const* d_in, const int* in_sizes, int n_in,
                              void* d_out, int out_size, void* d_ws,
                              size_t ws_size, hipStream_t stream) {
  const float* pre_feat = (const float*)d_in[0];
  const int* pre_coords = (const int*)d_in[1];
  const float* feats = (const float*)d_in[2];
  const float* KRcam = (const float*)d_in[3];
  const float* vol_origin = (const float*)d_in[4];
  const float* w2ac = (const float*)d_in[5];
  const float* W_sp = (const float*)d_in[6];
  const float* b_sp = (const float*)d_in[7];
  const float* W_t = (const float*)d_in[8];
  const float* b_t = (const float*)d_in[9];
  const float* W_o = (const float*)d_in[10];
  const float* b_o = (const float*)d_in[11];

  float* out = (float*)d_out;
  char* ws = (char*)d_ws;
  double* red = (double*)(ws + OFF_RED);
  int* tick = (int*)(ws + OFF_TICK);
  float* zst = (float*)(ws + OFF_ZST);
  uint4* tf16 = (uint4*)(ws + OFF_TF16);
  uint2* tf8 = (uint2*)(ws + OFF_TF8);
  float* pre_h = (float*)(ws + OFF_PREH);

  hipMemsetAsync(ws + OFF_TICK, 0, 64, stream);  // zero ticket (graph-safe)
  prep_kernel<<<NB_TF + NB_GEMM + NB_Z, 256, 0, stream>>>(
      feats, pre_feat, W_sp, b_sp, pre_coords, KRcam, vol_origin, tf16, tf8,
      pre_h, red, tick, zst);
  main_kernel<<<NB_Z, 256, 0, stream>>>(
      pre_coords, tf16, (const unsigned char*)tf8, KRcam, vol_origin, w2ac,
      W_sp, W_t, b_t, W_o, b_o, pre_h, out, zst);
}

// Round 8
// 139.924 us; speedup vs baseline: 1.2175x; 1.2175x over previous
//
#include <hip/hip_runtime.h>
#include <hip/hip_fp16.h>

#define Mpts 32768
#define Vv 9
#define Cc 24
#define Hh 120
#define Ww 160
#define Npts (Mpts * 8)          // 262144
#define PIX (Hh * Ww)            // 19200
#define VOXEL 0.04f

#define NB_TF   (Vv * 300)       // 2700 tf-convert blocks
#define NB_GEMM (Mpts / 256)     // 128 pre_h gemm blocks
#define NB_Z    (Npts / 256)     // 1024 z-stat blocks (and main blocks)

// ---------------- workspace layout (bytes) ----------------
// OFF_RED  : red[NB_Z][3] doubles — per-block z partials (each slot written
//            exactly once by its z-block; main reduces them — NO fences,
//            NO atomics: the kernel boundary provides ordering. R6 lesson:
//            device-scope fence per block = L2 writeback storm, +35 us.)
// OFF_TF16 : ch0-15  fp8, 16B/pixel (V,H,W)                   : 2764800 B
// OFF_TF8  : ch16-23 fp8,  8B/pixel (V,H,W)                   : 1382400 B
// OFF_PREH : pre_h (M,24) f32                                 : 3145728 B
// total tf footprint 4.15 MB ~ per-XCD L2.
#define OFF_RED   0
#define OFF_TF16  32768
#define OFF_TF8   (OFF_TF16 + Vv * PIX * 16)
#define OFF_PREH  (OFF_TF8 + Vv * PIX * 8)

typedef __attribute__((ext_vector_type(2))) float f32x2;
typedef __attribute__((ext_vector_type(4))) float f32x4;
typedef __attribute__((ext_vector_type(4))) int i32x4;

// 16B load with only 8B alignment guarantee (tf8 corner-pair tails).
__device__ __forceinline__ uint4 ld_u4_a8(const void* p) {
  struct __attribute__((packed, aligned(8))) A8 { uint4 v; };
  return ((const A8*)p)->v;
}

// pack 4 floats -> 4 fp8 e4m3 in one uint
__device__ __forceinline__ unsigned pack4fp8(float a, float b, float c,
                                             float d) {
  int u = __builtin_amdgcn_cvt_pk_fp8_f32(a, b, 0, false);
  u = __builtin_amdgcn_cvt_pk_fp8_f32(c, d, u, true);
  return (unsigned)u;
}

// ---------------- 1) prep: tf-convert | pre_h gemm | z-stats ---------------
__global__ __launch_bounds__(256) void prep_kernel(
    const float* __restrict__ feats, const float* __restrict__ pre_feat,
    const float* __restrict__ W_sp, const float* __restrict__ b_sp,
    const int* __restrict__ pre_coords, const float* __restrict__ KRcam,
    const float* __restrict__ vol_origin, uint4* __restrict__ tf16,
    uint2* __restrict__ tf8, float* __restrict__ pre_h,
    double* __restrict__ red) {
  __shared__ float tile[64][Cc + 1];   // tf path (6.4 KB)
  __shared__ float Wl[50 * Cc];        // gemm path (4.8 KB)
  __shared__ float bl[Cc];
  __shared__ float KRs[Vv * 12];       // z path
  __shared__ float origs[3];
  __shared__ float redl[3][4];
  int blk = blockIdx.x;

  if (blk < NB_TF) {
    // ---- feats(f32, C-major) -> tf16/tf8 (fp8, pixel-major) ----
    int v = blk / 300;
    int p0 = (blk % 300) * 64;
    const float* src = feats + (size_t)v * (Cc * PIX);
    for (int i = threadIdx.x; i < Cc * 64; i += 256) {
      int c = i >> 6, p = i & 63;
      tile[p][c] = __builtin_nontemporal_load(src + c * PIX + p0 + p);
    }
    __syncthreads();
    if (threadIdx.x < 64) {
      int p = threadIdx.x;
      const float* t = &tile[p][0];
      uint4 u;
      u.x = pack4fp8(t[0], t[1], t[2], t[3]);
      u.y = pack4fp8(t[4], t[5], t[6], t[7]);
      u.z = pack4fp8(t[8], t[9], t[10], t[11]);
      u.w = pack4fp8(t[12], t[13], t[14], t[15]);
      tf16[(size_t)v * PIX + p0 + p] = u;
    } else if (threadIdx.x < 128) {
      int p = threadIdx.x - 64;
      const float* t = &tile[p][0];
      uint2 u;
      u.x = pack4fp8(t[16], t[17], t[18], t[19]);
      u.y = pack4fp8(t[20], t[21], t[22], t[23]);
      tf8[(size_t)v * PIX + p0 + p] = u;
    }
  } else if (blk < NB_TF + NB_GEMM) {
    // ---- pre_h = pre_feat @ W_sp[25:75] + b ----
    int mb = blk - NB_TF;
    for (int i = threadIdx.x; i < 50 * Cc; i += 256) Wl[i] = W_sp[25 * Cc + i];
    if (threadIdx.x < Cc) bl[threadIdx.x] = b_sp[threadIdx.x];
    __syncthreads();
    int m = mb * 256 + threadIdx.x;
    float acc[Cc];
#pragma unroll
    for (int j = 0; j < Cc; j++) acc[j] = bl[j];
    const f32x2* pf = (const f32x2*)(pre_feat + (size_t)m * 50);
#pragma unroll 5
    for (int k = 0; k < 25; k++) {
      f32x2 x = __builtin_nontemporal_load(pf + k);
#pragma unroll
      for (int j = 0; j < Cc; j++)
        acc[j] += x.x * Wl[(2 * k) * Cc + j] + x.y * Wl[(2 * k + 1) * Cc + j];
    }
    f32x4* o4 = (f32x4*)(pre_h + (size_t)m * Cc);
#pragma unroll
    for (int t = 0; t < 6; t++) {
      f32x4 v4 = {acc[4 * t], acc[4 * t + 1], acc[4 * t + 2], acc[4 * t + 3]};
      o4[t] = v4;
    }
  } else {
    // ---- z-stat pass: projections only, per-block partial -> private slot --
    int zblk = blk - (NB_TF + NB_GEMM);
    for (int i = threadIdx.x; i < Vv * 12; i += 256) {
      int v = i / 12, r = i - v * 12;
      KRs[i] = KRcam[v * 16 + r];
    }
    if (threadIdx.x < 3) origs[threadIdx.x] = vol_origin[threadIdx.x];
    __syncthreads();
    int n = zblk * 256 + threadIdx.x;
    int m = n >> 3, o = n & 7;
    i32x4 pc = __builtin_nontemporal_load((const i32x4*)pre_coords + m);
    int cx = pc.y + ((0xB2 >> o) & 1);
    int cy = pc.z + ((0xD4 >> o) & 1);
    int cz = pc.w + ((0xE8 >> o) & 1);
    float wx0 = (float)cx * VOXEL + origs[0];
    float wy0 = (float)cy * VOXEL + origs[1];
    float wz0 = (float)cz * VOXEL + origs[2];
    float zsum = 0.f;
    int cnt = 0;
    for (int v = 0; v < Vv; v++) {
      const float* kr = &KRs[v * 12];
      float ix = kr[0] * wx0 + kr[1] * wy0 + kr[2] * wz0 + kr[3];
      float iy = kr[4] * wx0 + kr[5] * wy0 + kr[6] * wz0 + kr[7];
      float iz = kr[8] * wx0 + kr[9] * wy0 + kr[10] * wz0 + kr[11];
      float sz = (fabsf(iz) > 1e-9f) ? iz : 1e-9f;
      float px = ix / sz;
      float py = iy / sz;
      bool msk = (px >= 0.f) && (px <= (float)(Ww - 1)) && (py >= 0.f) &&
                 (py <= (float)(Hh - 1)) && (iz > 0.f);
      if (msk) {
        zsum += iz;
        cnt++;
      }
    }
    float denom = fmaxf((float)cnt, 1.f);
    float z = zsum / denom;
    float rz = (z > 0.f) ? z : 0.f;
    float rz2 = rz * rz;
    float rcn = (z > 0.f) ? 1.f : 0.f;
#pragma unroll
    for (int off = 32; off > 0; off >>= 1) {
      rz += __shfl_down(rz, off);
      rz2 += __shfl_down(rz2, off);
      rcn += __shfl_down(rcn, off);
    }
    int wid = threadIdx.x >> 6, lid = threadIdx.x & 63;
    if (lid == 0) {
      redl[0][wid] = rz;
      redl[1][wid] = rz2;
      redl[2][wid] = rcn;
    }
    __syncthreads();
    if (threadIdx.x == 0) {
      float a = 0.f, b = 0.f, c = 0.f;
#pragma unroll
      for (int w = 0; w < 4; w++) {
        a += redl[0][w];
        b += redl[1][w];
        c += redl[2][w];
      }
      double* r3 = red + (size_t)zblk * 3;
      r3[0] = (double)a;
      r3[1] = (double)b;
      r3[2] = (double)c;
    }
  }
}

// acc[0..15] += w * fp8x16(A)
__device__ __forceinline__ void acc16(uint4 A, float w, float* acc) {
#pragma unroll
  for (int t = 0; t < 4; t++) {
    unsigned u = ((const unsigned*)&A)[t];
    f32x2 f0 = __builtin_amdgcn_cvt_pk_f32_fp8((int)u, false);
    f32x2 f1 = __builtin_amdgcn_cvt_pk_f32_fp8((int)u, true);
    acc[4 * t + 0] += w * f0.x;
    acc[4 * t + 1] += w * f0.y;
    acc[4 * t + 2] += w * f1.x;
    acc[4 * t + 3] += w * f1.y;
  }
}
// acc[0..7] += w * fp8x8(ux,uy)
__device__ __forceinline__ void acc8v(unsigned ux, unsigned uy, float w,
                                      float* acc) {
  f32x2 f0 = __builtin_amdgcn_cvt_pk_f32_fp8((int)ux, false);
  f32x2 f1 = __builtin_amdgcn_cvt_pk_f32_fp8((int)ux, true);
  f32x2 f2 = __builtin_amdgcn_cvt_pk_f32_fp8((int)uy, false);
  f32x2 f3 = __builtin_amdgcn_cvt_pk_f32_fp8((int)uy, true);
  acc[0] += w * f0.x;
  acc[1] += w * f0.y;
  acc[2] += w * f1.x;
  acc[3] += w * f1.y;
  acc[4] += w * f2.x;
  acc[5] += w * f2.y;
  acc[6] += w * f3.x;
  acc[7] += w * f3.y;
}

// ---------------- 2) main: slot-reduce + gather (split tf) + fused heads ---
__global__ __launch_bounds__(256) void main_kernel(
    const int* __restrict__ pre_coords, const uint4* __restrict__ tf16,
    const unsigned char* __restrict__ tf8, const float* __restrict__ KRcam,
    const float* __restrict__ vol_origin, const float* __restrict__ w2ac,
    const float* __restrict__ W_sp, const float* __restrict__ W_t,
    const float* __restrict__ b_t, const float* __restrict__ W_o,
    const float* __restrict__ b_o, const float* __restrict__ pre_h,
    float* __restrict__ out, const double* __restrict__ red) {
  __shared__ float KR[Vv * 12];
  __shared__ float w2a[12];
  __shared__ float orig[3];
  __shared__ double dredl[3][4];
  __shared__ float s_zmean, s_izn;
  for (int i = threadIdx.x; i < Vv * 12; i += 256) {
    int v = i / 12, r = i - v * 12;
    KR[i] = KRcam[v * 16 + r];
  }
  if (threadIdx.x < 12) w2a[threadIdx.x] = w2ac[threadIdx.x];
  if (threadIdx.x < 3) orig[threadIdx.x] = vol_origin[threadIdx.x];

  {  // reduce the 1024 per-block partials -> zmean, 1/znorm (L2-hot, 24 KB)
    double a = 0.0, b = 0.0, c = 0.0;
    for (int s = threadIdx.x; s < NB_Z; s += 256) {
      const double* r3 = red + (size_t)s * 3;
      a += r3[0];
      b += r3[1];
      c += r3[2];
    }
#pragma unroll
    for (int off = 32; off > 0; off >>= 1) {
      a += __shfl_down(a, off);
      b += __shfl_down(b, off);
      c += __shfl_down(c, off);
    }
    int wid = threadIdx.x >> 6, lid = threadIdx.x & 63;
    if (lid == 0) {
      dredl[0][wid] = a;
      dredl[1][wid] = b;
      dredl[2][wid] = c;
    }
    __syncthreads();
    if (threadIdx.x == 0) {
      double A = 0.0, B = 0.0, C = 0.0;
#pragma unroll
      for (int w = 0; w < 4; w++) {
        A += dredl[0][w];
        B += dredl[1][w];
        C += dredl[2][w];
      }
      double npos = (C > 0.0) ? C : 1.0;
      double zmean = A / npos;
      double var = B - 2.0 * zmean * A + C * zmean * zmean;
      if (var < 0.0) var = 0.0;
      double znorm = sqrt(var) + 1e-5;
      s_zmean = (float)zmean;
      s_izn = (float)(1.0 / znorm);
    }
  }
  __syncthreads();

  int n = blockIdx.x * 256 + threadIdx.x;
  int m = n >> 3, o = n & 7;
  i32x4 pc = __builtin_nontemporal_load((const i32x4*)pre_coords + m);
  int cx = pc.y + ((0xB2 >> o) & 1);
  int cy = pc.z + ((0xD4 >> o) & 1);
  int cz = pc.w + ((0xE8 >> o) & 1);
  float wx0 = (float)cx * VOXEL + orig[0];
  float wy0 = (float)cy * VOXEL + orig[1];
  float wz0 = (float)cz * VOXEL + orig[2];

  {  // r_coords
    float camx = w2a[0] * wx0 + w2a[1] * wy0 + w2a[2] * wz0 + w2a[3];
    float camy = w2a[4] * wx0 + w2a[5] * wy0 + w2a[6] * wz0 + w2a[7];
    float camz = w2a[8] * wx0 + w2a[9] * wy0 + w2a[10] * wz0 + w2a[11];
    f32x4 rc = {camx, camy, camz, (float)pc.x};
    __builtin_nontemporal_store(rc, (f32x4*)(out + 3 * (size_t)Npts) + n);
  }

  float acc[Cc];
#pragma unroll
  for (int c = 0; c < Cc; c++) acc[c] = 0.f;
  float zsum = 0.f;
  int cnt = 0;

  for (int v = 0; v < Vv; v++) {
    const float* kr = &KR[v * 12];
    float ix = kr[0] * wx0 + kr[1] * wy0 + kr[2] * wz0 + kr[3];
    float iy = kr[4] * wx0 + kr[5] * wy0 + kr[6] * wz0 + kr[7];
    float iz = kr[8] * wx0 + kr[9] * wy0 + kr[10] * wz0 + kr[11];
    float sz = (fabsf(iz) > 1e-9f) ? iz : 1e-9f;
    float px = ix / sz;
    float py = iy / sz;
    bool msk = (px >= 0.f) && (px <= (float)(Ww - 1)) && (py >= 0.f) &&
               (py <= (float)(Hh - 1)) && (iz > 0.f);
    if (msk) {
      int x0 = (int)floorf(px), y0 = (int)floorf(py);
      int xs = min(x0, Ww - 2), ys = min(y0, Hh - 2);
      float wx = px - (float)xs, wy = py - (float)ys;
      float w00 = (1.f - wx) * (1.f - wy);
      float w10 = wx * (1.f - wy);
      float w01 = (1.f - wx) * wy;
      float w11 = wx * wy;
      size_t pp = (size_t)(v * PIX + ys * Ww + xs);
      const uint4* h16 = tf16 + pp;
      uint4 A = h16[0], B = h16[1];          // row ys, px xs/xs+1, ch0-15
      uint4 C = h16[Ww], D = h16[Ww + 1];    // row ys+1
      const unsigned char* t8 = tf8 + pp * 8;
      uint4 Tab = ld_u4_a8(t8);              // row ys: both tails in 16B
      uint4 Tcd = ld_u4_a8(t8 + Ww * 8);     // row ys+1
      acc16(A, w00, &acc[0]);
      acc16(B, w10, &acc[0]);
      acc16(C, w01, &acc[0]);
      acc16(D, w11, &acc[0]);
      acc8v(Tab.x, Tab.y, w00, &acc[16]);
      acc8v(Tab.z, Tab.w, w10, &acc[16]);
      acc8v(Tcd.x, Tcd.y, w01, &acc[16]);
      acc8v(Tcd.z, Tcd.w, w11, &acc[16]);
      zsum += iz;
      cnt++;
    }
  }

  float denom = fmaxf((float)cnt, 1.f);
  float invd = 1.f / denom;
  float z = zsum * invd;

  // h = pre_h[m] + (acc*invd) @ W_sp[0:24,:]  (W_sp: uniform scalar loads)
  float h[Cc];
  {
    const f32x4* ph4 = (const f32x4*)(pre_h + (size_t)m * Cc);
#pragma unroll
    for (int t = 0; t < 6; t++) {
      f32x4 v4 = ph4[t];
      h[4 * t + 0] = v4.x;
      h[4 * t + 1] = v4.y;
      h[4 * t + 2] = v4.z;
      h[4 * t + 3] = v4.w;
    }
  }
#pragma unroll
  for (int c = 0; c < Cc; c++) {
    float f = acc[c] * invd;
#pragma unroll
    for (int j = 0; j < Cc; j++) h[j] += f * W_sp[c * Cc + j];
  }

  // ---- fused finalize: zn channel + relu + heads, h never leaves regs ----
  float zn = (z > 0.f) ? (z - s_zmean) * s_izn : 0.f;
  float tsdf = b_t[0], occ = b_o[0];
#pragma unroll
  for (int j = 0; j < Cc; j++) {
    float hj = fmaxf(h[j] + zn * W_sp[24 * Cc + j], 0.f);
    tsdf += hj * W_t[j];
    occ += hj * W_o[j];
  }
  f32x2 o2 = {tsdf, occ};
  __builtin_nontemporal_store(o2, (f32x2*)out + n);
  __builtin_nontemporal_store((float)cnt, out + 2 * (size_t)Npts + n);
}

// ---------------- launch ---------------------------------------------------
extern "C" void kernel_launch(void* const* d_in, const int* in_sizes, int n_in,
                              void* d_out, int out_size, void* d_ws,
                              size_t ws_size, hipStream_t stream) {
  const float* pre_feat = (const float*)d_in[0];
  const int* pre_coords = (const int*)d_in[1];
  const float* feats = (const float*)d_in[2];
  const float* KRcam = (const float*)d_in[3];
  const float* vol_origin = (const float*)d_in[4];
  const float* w2ac = (const float*)d_in[5];
  const float* W_sp = (const float*)d_in[6];
  const float* b_sp = (const float*)d_in[7];
  const float* W_t = (const float*)d_in[8];
  const float* b_t = (const float*)d_in[9];
  const float* W_o = (const float*)d_in[10];
  const float* b_o = (const float*)d_in[11];

  float* out = (float*)d_out;
  char* ws = (char*)d_ws;
  double* red = (double*)(ws + OFF_RED);
  uint4* tf16 = (uint4*)(ws + OFF_TF16);
  uint2* tf8 = (uint2*)(ws + OFF_TF8);
  float* pre_h = (float*)(ws + OFF_PREH);

  prep_kernel<<<NB_TF + NB_GEMM + NB_Z, 256, 0, stream>>>(
      feats, pre_feat, W_sp, b_sp, pre_coords, KRcam, vol_origin, tf16, tf8,
      pre_h, red);
  main_kernel<<<NB_Z, 256, 0, stream>>>(
      pre_coords, tf16, (const unsigned char*)tf8, KRcam, vol_origin, w2ac,
      W_sp, W_t, b_t, W_o, b_o, pre_h, out, red);
}

// Round 9
// 135.463 us; speedup vs baseline: 1.2576x; 1.0329x over previous
//
#include <hip/hip_runtime.h>
#include <hip/hip_fp16.h>

#define Mpts 32768
#define Vv 9
#define Cc 24
#define Hh 120
#define Ww 160
#define Npts (Mpts * 8)          // 262144
#define PIX (Hh * Ww)            // 19200
#define VOXEL 0.04f

#define NB_TF   (Vv * 300)       // 2700 tf-convert blocks
#define NB_GEMM (Mpts / 256)     // 128 pre_h gemm blocks
#define NB_Z    (Npts / 256)     // 1024 z-stat blocks (and main blocks)

// ---------------- workspace layout (bytes) ----------------
// OFF_RED  : red[NB_Z][3] doubles — per-block z partials (each slot written
//            exactly once by its z-block; main reduces them — NO fences,
//            NO atomics: the kernel boundary provides ordering. R6 lesson:
//            device-scope fence per block = L2 writeback storm, +35 us.)
// OFF_TF16 : ch0-15  fp8, 16B/pixel (V,H,W)                   : 2764800 B
// OFF_TF8  : ch16-23 fp8,  8B/pixel (V,H,W)                   : 1382400 B
// OFF_PREH : pre_h (M,24) f32                                 : 3145728 B
// total tf footprint 4.15 MB ~ per-XCD L2.
#define OFF_RED   0
#define OFF_TF16  32768
#define OFF_TF8   (OFF_TF16 + Vv * PIX * 16)
#define OFF_PREH  (OFF_TF8 + Vv * PIX * 8)

typedef __attribute__((ext_vector_type(2))) float f32x2;
typedef __attribute__((ext_vector_type(4))) float f32x4;
typedef __attribute__((ext_vector_type(4))) int i32x4;

// 16B load with only 8B alignment guarantee (tf8 corner-pair tails).
__device__ __forceinline__ uint4 ld_u4_a8(const void* p) {
  struct __attribute__((packed, aligned(8))) A8 { uint4 v; };
  return ((const A8*)p)->v;
}

// pack 4 floats -> 4 fp8 e4m3 in one uint
__device__ __forceinline__ unsigned pack4fp8(float a, float b, float c,
                                             float d) {
  int u = __builtin_amdgcn_cvt_pk_fp8_f32(a, b, 0, false);
  u = __builtin_amdgcn_cvt_pk_fp8_f32(c, d, u, true);
  return (unsigned)u;
}

// ---------------- 1) prep: tf-convert | pre_h gemm | z-stats+r_coords ------
__global__ __launch_bounds__(256) void prep_kernel(
    const float* __restrict__ feats, const float* __restrict__ pre_feat,
    const float* __restrict__ W_sp, const float* __restrict__ b_sp,
    const int* __restrict__ pre_coords, const float* __restrict__ KRcam,
    const float* __restrict__ vol_origin, const float* __restrict__ w2ac,
    uint4* __restrict__ tf16, uint2* __restrict__ tf8,
    float* __restrict__ pre_h, double* __restrict__ red,
    float* __restrict__ out) {
  __shared__ float tile[64][Cc + 1];   // tf path (6.4 KB)
  __shared__ float Wl[50 * Cc];        // gemm path (4.8 KB)
  __shared__ float bl[Cc];
  __shared__ float KRs[Vv * 12];       // z path
  __shared__ float origs[3];
  __shared__ float redl[3][4];
  int blk = blockIdx.x;

  if (blk < NB_TF) {
    // ---- feats(f32, C-major) -> tf16/tf8 (fp8, pixel-major) ----
    int v = blk / 300;
    int p0 = (blk % 300) * 64;
    const float* src = feats + (size_t)v * (Cc * PIX);
    for (int i = threadIdx.x; i < Cc * 16; i += 256) {  // f32x4 staging
      int c = i >> 4, p4 = (i & 15) * 4;
      f32x4 x = __builtin_nontemporal_load(
          (const f32x4*)(src + (size_t)c * PIX + p0 + p4));
      tile[p4 + 0][c] = x.x;
      tile[p4 + 1][c] = x.y;
      tile[p4 + 2][c] = x.z;
      tile[p4 + 3][c] = x.w;
    }
    __syncthreads();
    if (threadIdx.x < 64) {
      int p = threadIdx.x;
      const float* t = &tile[p][0];
      uint4 u;
      u.x = pack4fp8(t[0], t[1], t[2], t[3]);
      u.y = pack4fp8(t[4], t[5], t[6], t[7]);
      u.z = pack4fp8(t[8], t[9], t[10], t[11]);
      u.w = pack4fp8(t[12], t[13], t[14], t[15]);
      tf16[(size_t)v * PIX + p0 + p] = u;
    } else if (threadIdx.x < 128) {
      int p = threadIdx.x - 64;
      const float* t = &tile[p][0];
      uint2 u;
      u.x = pack4fp8(t[16], t[17], t[18], t[19]);
      u.y = pack4fp8(t[20], t[21], t[22], t[23]);
      tf8[(size_t)v * PIX + p0 + p] = u;
    }
  } else if (blk < NB_TF + NB_GEMM) {
    // ---- pre_h = pre_feat @ W_sp[25:75] + b ----
    int mb = blk - NB_TF;
    for (int i = threadIdx.x; i < 50 * Cc; i += 256) Wl[i] = W_sp[25 * Cc + i];
    if (threadIdx.x < Cc) bl[threadIdx.x] = b_sp[threadIdx.x];
    __syncthreads();
    int m = mb * 256 + threadIdx.x;
    float acc[Cc];
#pragma unroll
    for (int j = 0; j < Cc; j++) acc[j] = bl[j];
    const f32x2* pf = (const f32x2*)(pre_feat + (size_t)m * 50);
#pragma unroll 5
    for (int k = 0; k < 25; k++) {
      f32x2 x = __builtin_nontemporal_load(pf + k);
#pragma unroll
      for (int j = 0; j < Cc; j++)
        acc[j] += x.x * Wl[(2 * k) * Cc + j] + x.y * Wl[(2 * k + 1) * Cc + j];
    }
    f32x4* o4 = (f32x4*)(pre_h + (size_t)m * Cc);
#pragma unroll
    for (int t = 0; t < 6; t++) {
      f32x4 v4 = {acc[4 * t], acc[4 * t + 1], acc[4 * t + 2], acc[4 * t + 3]};
      o4[t] = v4;
    }
  } else {
    // ---- z-stat pass: projections + r_coords; partial -> private slot ----
    int zblk = blk - (NB_TF + NB_GEMM);
    for (int i = threadIdx.x; i < Vv * 12; i += 256) {
      int v = i / 12, r = i - v * 12;
      KRs[i] = KRcam[v * 16 + r];
    }
    if (threadIdx.x < 3) origs[threadIdx.x] = vol_origin[threadIdx.x];
    __syncthreads();
    int n = zblk * 256 + threadIdx.x;
    int m = n >> 3, o = n & 7;
    i32x4 pc = __builtin_nontemporal_load((const i32x4*)pre_coords + m);
    int cx = pc.y + ((0xB2 >> o) & 1);
    int cy = pc.z + ((0xD4 >> o) & 1);
    int cz = pc.w + ((0xE8 >> o) & 1);
    float wx0 = (float)cx * VOXEL + origs[0];
    float wy0 = (float)cy * VOXEL + origs[1];
    float wz0 = (float)cz * VOXEL + origs[2];

    {  // r_coords (moved from main; w2ac reads are uniform -> s_loads)
      float camx = w2ac[0] * wx0 + w2ac[1] * wy0 + w2ac[2] * wz0 + w2ac[3];
      float camy = w2ac[4] * wx0 + w2ac[5] * wy0 + w2ac[6] * wz0 + w2ac[7];
      float camz = w2ac[8] * wx0 + w2ac[9] * wy0 + w2ac[10] * wz0 + w2ac[11];
      f32x4 rc = {camx, camy, camz, (float)pc.x};
      __builtin_nontemporal_store(rc, (f32x4*)(out + 3 * (size_t)Npts) + n);
    }

    float zsum = 0.f;
    int cnt = 0;
    for (int v = 0; v < Vv; v++) {
      const float* kr = &KRs[v * 12];
      float ix = kr[0] * wx0 + kr[1] * wy0 + kr[2] * wz0 + kr[3];
      float iy = kr[4] * wx0 + kr[5] * wy0 + kr[6] * wz0 + kr[7];
      float iz = kr[8] * wx0 + kr[9] * wy0 + kr[10] * wz0 + kr[11];
      float sz = (fabsf(iz) > 1e-9f) ? iz : 1e-9f;
      float px = ix / sz;
      float py = iy / sz;
      bool msk = (px >= 0.f) && (px <= (float)(Ww - 1)) && (py >= 0.f) &&
                 (py <= (float)(Hh - 1)) && (iz > 0.f);
      if (msk) {
        zsum += iz;
        cnt++;
      }
    }
    float denom = fmaxf((float)cnt, 1.f);
    float z = zsum / denom;
    float rz = (z > 0.f) ? z : 0.f;
    float rz2 = rz * rz;
    float rcn = (z > 0.f) ? 1.f : 0.f;
#pragma unroll
    for (int off = 32; off > 0; off >>= 1) {
      rz += __shfl_down(rz, off);
      rz2 += __shfl_down(rz2, off);
      rcn += __shfl_down(rcn, off);
    }
    int wid = threadIdx.x >> 6, lid = threadIdx.x & 63;
    if (lid == 0) {
      redl[0][wid] = rz;
      redl[1][wid] = rz2;
      redl[2][wid] = rcn;
    }
    __syncthreads();
    if (threadIdx.x == 0) {
      float a = 0.f, b = 0.f, c = 0.f;
#pragma unroll
      for (int w = 0; w < 4; w++) {
        a += redl[0][w];
        b += redl[1][w];
        c += redl[2][w];
      }
      double* r3 = red + (size_t)zblk * 3;
      r3[0] = (double)a;
      r3[1] = (double)b;
      r3[2] = (double)c;
    }
  }
}

// acc[0..15] += w * fp8x16(A)
__device__ __forceinline__ void acc16(uint4 A, float w, float* acc) {
#pragma unroll
  for (int t = 0; t < 4; t++) {
    unsigned u = ((const unsigned*)&A)[t];
    f32x2 f0 = __builtin_amdgcn_cvt_pk_f32_fp8((int)u, false);
    f32x2 f1 = __builtin_amdgcn_cvt_pk_f32_fp8((int)u, true);
    acc[4 * t + 0] += w * f0.x;
    acc[4 * t + 1] += w * f0.y;
    acc[4 * t + 2] += w * f1.x;
    acc[4 * t + 3] += w * f1.y;
  }
}
// acc[0..7] += w * fp8x8(ux,uy)
__device__ __forceinline__ void acc8v(unsigned ux, unsigned uy, float w,
                                      float* acc) {
  f32x2 f0 = __builtin_amdgcn_cvt_pk_f32_fp8((int)ux, false);
  f32x2 f1 = __builtin_amdgcn_cvt_pk_f32_fp8((int)ux, true);
  f32x2 f2 = __builtin_amdgcn_cvt_pk_f32_fp8((int)uy, false);
  f32x2 f3 = __builtin_amdgcn_cvt_pk_f32_fp8((int)uy, true);
  acc[0] += w * f0.x;
  acc[1] += w * f0.y;
  acc[2] += w * f1.x;
  acc[3] += w * f1.y;
  acc[4] += w * f2.x;
  acc[5] += w * f2.y;
  acc[6] += w * f3.x;
  acc[7] += w * f3.y;
}

// ---------------- 2) main: slot-reduce + gather (split tf) + fused heads ---
// __launch_bounds__(256,4): grid supplies only 4 waves/SIMD, so allow the
// full 128-VGPR budget for that occupancy (scheduler slack for gathers).
__global__ __launch_bounds__(256, 4) void main_kernel(
    const int* __restrict__ pre_coords, const uint4* __restrict__ tf16,
    const unsigned char* __restrict__ tf8, const float* __restrict__ KRcam,
    const float* __restrict__ vol_origin, const float* __restrict__ W_sp,
    const float* __restrict__ W_t, const float* __restrict__ b_t,
    const float* __restrict__ W_o, const float* __restrict__ b_o,
    const float* __restrict__ pre_h, float* __restrict__ out,
    const double* __restrict__ red) {
  __shared__ float KR[Vv * 12];
  __shared__ float orig[3];
  __shared__ double dredl[3][4];
  __shared__ float s_zmean, s_izn;
  for (int i = threadIdx.x; i < Vv * 12; i += 256) {
    int v = i / 12, r = i - v * 12;
    KR[i] = KRcam[v * 16 + r];
  }
  if (threadIdx.x < 3) orig[threadIdx.x] = vol_origin[threadIdx.x];

  {  // reduce the 1024 per-block partials -> zmean, 1/znorm (L2-hot, 24 KB)
    double a = 0.0, b = 0.0, c = 0.0;
    for (int s = threadIdx.x; s < NB_Z; s += 256) {
      const double* r3 = red + (size_t)s * 3;
      a += r3[0];
      b += r3[1];
      c += r3[2];
    }
#pragma unroll
    for (int off = 32; off > 0; off >>= 1) {
      a += __shfl_down(a, off);
      b += __shfl_down(b, off);
      c += __shfl_down(c, off);
    }
    int wid = threadIdx.x >> 6, lid = threadIdx.x & 63;
    if (lid == 0) {
      dredl[0][wid] = a;
      dredl[1][wid] = b;
      dredl[2][wid] = c;
    }
    __syncthreads();
    if (threadIdx.x == 0) {
      double A = 0.0, B = 0.0, C = 0.0;
#pragma unroll
      for (int w = 0; w < 4; w++) {
        A += dredl[0][w];
        B += dredl[1][w];
        C += dredl[2][w];
      }
      double npos = (C > 0.0) ? C : 1.0;
      double zmean = A / npos;
      double var = B - 2.0 * zmean * A + C * zmean * zmean;
      if (var < 0.0) var = 0.0;
      double znorm = sqrt(var) + 1e-5;
      s_zmean = (float)zmean;
      s_izn = (float)(1.0 / znorm);
    }
  }
  __syncthreads();

  int n = blockIdx.x * 256 + threadIdx.x;
  int m = n >> 3, o = n & 7;
  i32x4 pc = __builtin_nontemporal_load((const i32x4*)pre_coords + m);
  int cx = pc.y + ((0xB2 >> o) & 1);
  int cy = pc.z + ((0xD4 >> o) & 1);
  int cz = pc.w + ((0xE8 >> o) & 1);
  float wx0 = (float)cx * VOXEL + orig[0];
  float wy0 = (float)cy * VOXEL + orig[1];
  float wz0 = (float)cz * VOXEL + orig[2];

  float acc[Cc];
#pragma unroll
  for (int c = 0; c < Cc; c++) acc[c] = 0.f;
  float zsum = 0.f;
  int cnt = 0;

  for (int v = 0; v < Vv; v++) {
    const float* kr = &KR[v * 12];
    float ix = kr[0] * wx0 + kr[1] * wy0 + kr[2] * wz0 + kr[3];
    float iy = kr[4] * wx0 + kr[5] * wy0 + kr[6] * wz0 + kr[7];
    float iz = kr[8] * wx0 + kr[9] * wy0 + kr[10] * wz0 + kr[11];
    float sz = (fabsf(iz) > 1e-9f) ? iz : 1e-9f;
    float px = ix / sz;
    float py = iy / sz;
    bool msk = (px >= 0.f) && (px <= (float)(Ww - 1)) && (py >= 0.f) &&
               (py <= (float)(Hh - 1)) && (iz > 0.f);
    if (msk) {
      int x0 = (int)floorf(px), y0 = (int)floorf(py);
      int xs = min(x0, Ww - 2), ys = min(y0, Hh - 2);
      float wx = px - (float)xs, wy = py - (float)ys;
      float w00 = (1.f - wx) * (1.f - wy);
      float w10 = wx * (1.f - wy);
      float w01 = (1.f - wx) * wy;
      float w11 = wx * wy;
      size_t pp = (size_t)(v * PIX + ys * Ww + xs);
      const uint4* h16 = tf16 + pp;
      uint4 A = h16[0], B = h16[1];          // row ys, px xs/xs+1, ch0-15
      uint4 C = h16[Ww], D = h16[Ww + 1];    // row ys+1
      const unsigned char* t8 = tf8 + pp * 8;
      uint4 Tab = ld_u4_a8(t8);              // row ys: both tails in 16B
      uint4 Tcd = ld_u4_a8(t8 + Ww * 8);     // row ys+1
      acc16(A, w00, &acc[0]);
      acc16(B, w10, &acc[0]);
      acc16(C, w01, &acc[0]);
      acc16(D, w11, &acc[0]);
      acc8v(Tab.x, Tab.y, w00, &acc[16]);
      acc8v(Tab.z, Tab.w, w10, &acc[16]);
      acc8v(Tcd.x, Tcd.y, w01, &acc[16]);
      acc8v(Tcd.z, Tcd.w, w11, &acc[16]);
      zsum += iz;
      cnt++;
    }
  }

  float denom = fmaxf((float)cnt, 1.f);
  float invd = 1.f / denom;
  float z = zsum * invd;

  // h = pre_h[m] + (acc*invd) @ W_sp[0:24,:]  (W_sp: uniform scalar loads)
  float h[Cc];
  {
    const f32x4* ph4 = (const f32x4*)(pre_h + (size_t)m * Cc);
#pragma unroll
    for (int t = 0; t < 6; t++) {
      f32x4 v4 = ph4[t];
      h[4 * t + 0] = v4.x;
      h[4 * t + 1] = v4.y;
      h[4 * t + 2] = v4.z;
      h[4 * t + 3] = v4.w;
    }
  }
#pragma unroll
  for (int c = 0; c < Cc; c++) {
    float f = acc[c] * invd;
#pragma unroll
    for (int j = 0; j < Cc; j++) h[j] += f * W_sp[c * Cc + j];
  }

  // ---- fused finalize: zn channel + relu + heads, h never leaves regs ----
  float zn = (z > 0.f) ? (z - s_zmean) * s_izn : 0.f;
  float tsdf = b_t[0], occ = b_o[0];
#pragma unroll
  for (int j = 0; j < Cc; j++) {
    float hj = fmaxf(h[j] + zn * W_sp[24 * Cc + j], 0.f);
    tsdf += hj * W_t[j];
    occ += hj * W_o[j];
  }
  f32x2 o2 = {tsdf, occ};
  __builtin_nontemporal_store(o2, (f32x2*)out + n);
  __builtin_nontemporal_store((float)cnt, out + 2 * (size_t)Npts + n);
}

// ---------------- launch ---------------------------------------------------
extern "C" void kernel_launch(void* const* d_in, const int* in_sizes, int n_in,
                              void* d_out, int out_size, void* d_ws,
                              size_t ws_size, hipStream_t stream) {
  const float* pre_feat = (const float*)d_in[0];
  const int* pre_coords = (const int*)d_in[1];
  const float* feats = (const float*)d_in[2];
  const float* KRcam = (const float*)d_in[3];
  const float* vol_origin = (const float*)d_in[4];
  const float* w2ac = (const float*)d_in[5];
  const float* W_sp = (const float*)d_in[6];
  const float* b_sp = (const float*)d_in[7];
  const float* W_t = (const float*)d_in[8];
  const float* b_t = (const float*)d_in[9];
  const float* W_o = (const float*)d_in[10];
  const float* b_o = (const float*)d_in[11];

  float* out = (float*)d_out;
  char* ws = (char*)d_ws;
  double* red = (double*)(ws + OFF_RED);
  uint4* tf16 = (uint4*)(ws + OFF_TF16);
  uint2* tf8 = (uint2*)(ws + OFF_TF8);
  float* pre_h = (float*)(ws + OFF_PREH);

  prep_kernel<<<NB_TF + NB_GEMM + NB_Z, 256, 0, stream>>>(
      feats, pre_feat, W_sp, b_sp, pre_coords, KRcam, vol_origin, w2ac, tf16,
      tf8, pre_h, red, out);
  main_kernel<<<NB_Z, 256, 0, stream>>>(
      pre_coords, tf16, (const unsigned char*)tf8, KRcam, vol_origin, W_sp,
      W_t, b_t, W_o, b_o, pre_h, out, red);
}

// Round 10
// 128.715 us; speedup vs baseline: 1.3235x; 1.0524x over previous
//
#include <hip/hip_runtime.h>
#include <hip/hip_fp16.h>

#define Mpts 32768
#define Vv 9
#define Cc 24
#define Hh 120
#define Ww 160
#define Npts (Mpts * 8)          // 262144
#define PIX (Hh * Ww)            // 19200
#define VOXEL 0.04f

#define NB_TF   ((Vv * PIX) / 256)  // 675 direct per-pixel tf blocks
#define NB_GEMM (Mpts / 256)        // 128 pre_h gemm blocks
#define NB_Z    (Npts / 256)        // 1024 z-stat blocks (and main blocks)

// ---------------- workspace layout (bytes) ----------------
// OFF_RED  : red[NB_Z][3] doubles — per-block z partials (each slot written
//            exactly once by its z-block; main reduces them — NO fences,
//            NO atomics: the kernel boundary provides ordering. R6 lesson:
//            device-scope fence per block = L2 writeback storm, +35 us.)
// OFF_TF16 : ch0-15  fp8, 16B/pixel (V,H,W)                   : 2764800 B
// OFF_TF8  : ch16-23 fp8,  8B/pixel (V,H,W)                   : 1382400 B
// OFF_PREH : pre_h (M,24) f32                                 : 3145728 B
// total tf footprint 4.15 MB ~ per-XCD L2.
#define OFF_RED   0
#define OFF_TF16  32768
#define OFF_TF8   (OFF_TF16 + Vv * PIX * 16)
#define OFF_PREH  (OFF_TF8 + Vv * PIX * 8)

typedef __attribute__((ext_vector_type(2))) float f32x2;
typedef __attribute__((ext_vector_type(4))) float f32x4;
typedef __attribute__((ext_vector_type(4))) int i32x4;

// 16B load with only 8B alignment guarantee (tf8 corner-pair tails).
__device__ __forceinline__ uint4 ld_u4_a8(const void* p) {
  struct __attribute__((packed, aligned(8))) A8 { uint4 v; };
  return ((const A8*)p)->v;
}

// pack 4 floats -> 4 fp8 e4m3 in one uint
__device__ __forceinline__ unsigned pack4fp8(float a, float b, float c,
                                             float d) {
  int u = __builtin_amdgcn_cvt_pk_fp8_f32(a, b, 0, false);
  u = __builtin_amdgcn_cvt_pk_fp8_f32(c, d, u, true);
  return (unsigned)u;
}

// ---------------- 1) prep: tf-convert | pre_h gemm | z-stats+r_coords ------
__global__ __launch_bounds__(256) void prep_kernel(
    const float* __restrict__ feats, const float* __restrict__ pre_feat,
    const float* __restrict__ W_sp, const float* __restrict__ b_sp,
    const int* __restrict__ pre_coords, const float* __restrict__ KRcam,
    const float* __restrict__ vol_origin, const float* __restrict__ w2ac,
    uint4* __restrict__ tf16, uint2* __restrict__ tf8,
    float* __restrict__ pre_h, double* __restrict__ red,
    float* __restrict__ out) {
  __shared__ float Wl[50 * Cc];        // gemm path (4.8 KB)
  __shared__ float bl[Cc];
  __shared__ float KRs[Vv * 12];       // z path
  __shared__ float origs[3];
  __shared__ float redl[3][4];
  int blk = blockIdx.x;

  if (blk < NB_TF) {
    // ---- feats(f32, C-major) -> tf16/tf8: direct per-pixel, no LDS ----
    // One thread = one pixel; channel loads coalesce across the wave
    // (64 lanes x 4B = 256B segment per channel). PIX%256==0 -> block
    // never crosses a view boundary.
    int gp = blk * 256 + threadIdx.x;        // global pixel, 0..Vv*PIX
    int v = gp / PIX;
    int p = gp - v * PIX;
    const float* src = feats + (size_t)v * (Cc * PIX) + p;
    float t[Cc];
#pragma unroll
    for (int c = 0; c < Cc; c++)
      t[c] = __builtin_nontemporal_load(src + (size_t)c * PIX);
    uint4 u;
    u.x = pack4fp8(t[0], t[1], t[2], t[3]);
    u.y = pack4fp8(t[4], t[5], t[6], t[7]);
    u.z = pack4fp8(t[8], t[9], t[10], t[11]);
    u.w = pack4fp8(t[12], t[13], t[14], t[15]);
    tf16[gp] = u;
    uint2 u2;
    u2.x = pack4fp8(t[16], t[17], t[18], t[19]);
    u2.y = pack4fp8(t[20], t[21], t[22], t[23]);
    tf8[gp] = u2;
  } else if (blk < NB_TF + NB_GEMM) {
    // ---- pre_h = pre_feat @ W_sp[25:75] + b ----
    int mb = blk - NB_TF;
    for (int i = threadIdx.x; i < 50 * Cc; i += 256) Wl[i] = W_sp[25 * Cc + i];
    if (threadIdx.x < Cc) bl[threadIdx.x] = b_sp[threadIdx.x];
    __syncthreads();
    int m = mb * 256 + threadIdx.x;
    float acc[Cc];
#pragma unroll
    for (int j = 0; j < Cc; j++) acc[j] = bl[j];
    const f32x2* pf = (const f32x2*)(pre_feat + (size_t)m * 50);
#pragma unroll 5
    for (int k = 0; k < 25; k++) {
      f32x2 x = __builtin_nontemporal_load(pf + k);
#pragma unroll
      for (int j = 0; j < Cc; j++)
        acc[j] += x.x * Wl[(2 * k) * Cc + j] + x.y * Wl[(2 * k + 1) * Cc + j];
    }
    f32x4* o4 = (f32x4*)(pre_h + (size_t)m * Cc);
#pragma unroll
    for (int t = 0; t < 6; t++) {
      f32x4 v4 = {acc[4 * t], acc[4 * t + 1], acc[4 * t + 2], acc[4 * t + 3]};
      o4[t] = v4;
    }
  } else {
    // ---- z-stat pass: projections + r_coords; partial -> private slot ----
    int zblk = blk - (NB_TF + NB_GEMM);
    for (int i = threadIdx.x; i < Vv * 12; i += 256) {
      int v = i / 12, r = i - v * 12;
      KRs[i] = KRcam[v * 16 + r];
    }
    if (threadIdx.x < 3) origs[threadIdx.x] = vol_origin[threadIdx.x];
    __syncthreads();
    int n = zblk * 256 + threadIdx.x;
    int m = n >> 3, o = n & 7;
    i32x4 pc = __builtin_nontemporal_load((const i32x4*)pre_coords + m);
    int cx = pc.y + ((0xB2 >> o) & 1);
    int cy = pc.z + ((0xD4 >> o) & 1);
    int cz = pc.w + ((0xE8 >> o) & 1);
    float wx0 = (float)cx * VOXEL + origs[0];
    float wy0 = (float)cy * VOXEL + origs[1];
    float wz0 = (float)cz * VOXEL + origs[2];

    {  // r_coords (w2ac reads are uniform -> s_loads)
      float camx = w2ac[0] * wx0 + w2ac[1] * wy0 + w2ac[2] * wz0 + w2ac[3];
      float camy = w2ac[4] * wx0 + w2ac[5] * wy0 + w2ac[6] * wz0 + w2ac[7];
      float camz = w2ac[8] * wx0 + w2ac[9] * wy0 + w2ac[10] * wz0 + w2ac[11];
      f32x4 rc = {camx, camy, camz, (float)pc.x};
      __builtin_nontemporal_store(rc, (f32x4*)(out + 3 * (size_t)Npts) + n);
    }

    float zsum = 0.f;
    int cnt = 0;
    for (int v = 0; v < Vv; v++) {
      const float* kr = &KRs[v * 12];
      float ix = kr[0] * wx0 + kr[1] * wy0 + kr[2] * wz0 + kr[3];
      float iy = kr[4] * wx0 + kr[5] * wy0 + kr[6] * wz0 + kr[7];
      float iz = kr[8] * wx0 + kr[9] * wy0 + kr[10] * wz0 + kr[11];
      float sz = (fabsf(iz) > 1e-9f) ? iz : 1e-9f;
      float px = ix / sz;
      float py = iy / sz;
      bool msk = (px >= 0.f) && (px <= (float)(Ww - 1)) && (py >= 0.f) &&
                 (py <= (float)(Hh - 1)) && (iz > 0.f);
      if (msk) {
        zsum += iz;
        cnt++;
      }
    }
    float denom = fmaxf((float)cnt, 1.f);
    float z = zsum / denom;
    float rz = (z > 0.f) ? z : 0.f;
    float rz2 = rz * rz;
    float rcn = (z > 0.f) ? 1.f : 0.f;
#pragma unroll
    for (int off = 32; off > 0; off >>= 1) {
      rz += __shfl_down(rz, off);
      rz2 += __shfl_down(rz2, off);
      rcn += __shfl_down(rcn, off);
    }
    int wid = threadIdx.x >> 6, lid = threadIdx.x & 63;
    if (lid == 0) {
      redl[0][wid] = rz;
      redl[1][wid] = rz2;
      redl[2][wid] = rcn;
    }
    __syncthreads();
    if (threadIdx.x == 0) {
      float a = 0.f, b = 0.f, c = 0.f;
#pragma unroll
      for (int w = 0; w < 4; w++) {
        a += redl[0][w];
        b += redl[1][w];
        c += redl[2][w];
      }
      double* r3 = red + (size_t)zblk * 3;
      r3[0] = (double)a;
      r3[1] = (double)b;
      r3[2] = (double)c;
    }
  }
}

// acc[0..15] += w * fp8x16(A)
__device__ __forceinline__ void acc16(uint4 A, float w, float* acc) {
#pragma unroll
  for (int t = 0; t < 4; t++) {
    unsigned u = ((const unsigned*)&A)[t];
    f32x2 f0 = __builtin_amdgcn_cvt_pk_f32_fp8((int)u, false);
    f32x2 f1 = __builtin_amdgcn_cvt_pk_f32_fp8((int)u, true);
    acc[4 * t + 0] += w * f0.x;
    acc[4 * t + 1] += w * f0.y;
    acc[4 * t + 2] += w * f1.x;
    acc[4 * t + 3] += w * f1.y;
  }
}
// acc[0..7] += w * fp8x8(ux,uy)
__device__ __forceinline__ void acc8v(unsigned ux, unsigned uy, float w,
                                      float* acc) {
  f32x2 f0 = __builtin_amdgcn_cvt_pk_f32_fp8((int)ux, false);
  f32x2 f1 = __builtin_amdgcn_cvt_pk_f32_fp8((int)ux, true);
  f32x2 f2 = __builtin_amdgcn_cvt_pk_f32_fp8((int)uy, false);
  f32x2 f3 = __builtin_amdgcn_cvt_pk_f32_fp8((int)uy, true);
  acc[0] += w * f0.x;
  acc[1] += w * f0.y;
  acc[2] += w * f1.x;
  acc[3] += w * f1.y;
  acc[4] += w * f2.x;
  acc[5] += w * f2.y;
  acc[6] += w * f3.x;
  acc[7] += w * f3.y;
}

// ---------------- 2) main: slot-reduce + gather (split tf) + fused heads ---
// __launch_bounds__(256,4): grid supplies only 4 waves/SIMD, so allow the
// full 128-VGPR budget for that occupancy (scheduler slack for gathers).
__global__ __launch_bounds__(256, 4) void main_kernel(
    const int* __restrict__ pre_coords, const uint4* __restrict__ tf16,
    const unsigned char* __restrict__ tf8, const float* __restrict__ KRcam,
    const float* __restrict__ vol_origin, const float* __restrict__ W_sp,
    const float* __restrict__ W_t, const float* __restrict__ b_t,
    const float* __restrict__ W_o, const float* __restrict__ b_o,
    const float* __restrict__ pre_h, float* __restrict__ out,
    const double* __restrict__ red) {
  __shared__ float KR[Vv * 12];
  __shared__ float orig[3];
  __shared__ double dredl[3][4];
  __shared__ float s_zmean, s_izn;
  for (int i = threadIdx.x; i < Vv * 12; i += 256) {
    int v = i / 12, r = i - v * 12;
    KR[i] = KRcam[v * 16 + r];
  }
  if (threadIdx.x < 3) orig[threadIdx.x] = vol_origin[threadIdx.x];

  {  // reduce the 1024 per-block partials -> zmean, 1/znorm (L2-hot, 24 KB)
    double a = 0.0, b = 0.0, c = 0.0;
    for (int s = threadIdx.x; s < NB_Z; s += 256) {
      const double* r3 = red + (size_t)s * 3;
      a += r3[0];
      b += r3[1];
      c += r3[2];
    }
#pragma unroll
    for (int off = 32; off > 0; off >>= 1) {
      a += __shfl_down(a, off);
      b += __shfl_down(b, off);
      c += __shfl_down(c, off);
    }
    int wid = threadIdx.x >> 6, lid = threadIdx.x & 63;
    if (lid == 0) {
      dredl[0][wid] = a;
      dredl[1][wid] = b;
      dredl[2][wid] = c;
    }
    __syncthreads();
    if (threadIdx.x == 0) {
      double A = 0.0, B = 0.0, C = 0.0;
#pragma unroll
      for (int w = 0; w < 4; w++) {
        A += dredl[0][w];
        B += dredl[1][w];
        C += dredl[2][w];
      }
      double npos = (C > 0.0) ? C : 1.0;
      double zmean = A / npos;
      double var = B - 2.0 * zmean * A + C * zmean * zmean;
      if (var < 0.0) var = 0.0;
      double znorm = sqrt(var) + 1e-5;
      s_zmean = (float)zmean;
      s_izn = (float)(1.0 / znorm);
    }
  }
  __syncthreads();

  int n = blockIdx.x * 256 + threadIdx.x;
  int m = n >> 3, o = n & 7;
  i32x4 pc = __builtin_nontemporal_load((const i32x4*)pre_coords + m);
  int cx = pc.y + ((0xB2 >> o) & 1);
  int cy = pc.z + ((0xD4 >> o) & 1);
  int cz = pc.w + ((0xE8 >> o) & 1);
  float wx0 = (float)cx * VOXEL + orig[0];
  float wy0 = (float)cy * VOXEL + orig[1];
  float wz0 = (float)cz * VOXEL + orig[2];

  float acc[Cc];
#pragma unroll
  for (int c = 0; c < Cc; c++) acc[c] = 0.f;
  float zsum = 0.f;
  int cnt = 0;

  for (int v = 0; v < Vv; v++) {
    const float* kr = &KR[v * 12];
    float ix = kr[0] * wx0 + kr[1] * wy0 + kr[2] * wz0 + kr[3];
    float iy = kr[4] * wx0 + kr[5] * wy0 + kr[6] * wz0 + kr[7];
    float iz = kr[8] * wx0 + kr[9] * wy0 + kr[10] * wz0 + kr[11];
    float sz = (fabsf(iz) > 1e-9f) ? iz : 1e-9f;
    float px = ix / sz;
    float py = iy / sz;
    bool msk = (px >= 0.f) && (px <= (float)(Ww - 1)) && (py >= 0.f) &&
               (py <= (float)(Hh - 1)) && (iz > 0.f);
    if (msk) {
      int x0 = (int)floorf(px), y0 = (int)floorf(py);
      int xs = min(x0, Ww - 2), ys = min(y0, Hh - 2);
      float wx = px - (float)xs, wy = py - (float)ys;
      float w00 = (1.f - wx) * (1.f - wy);
      float w10 = wx * (1.f - wy);
      float w01 = (1.f - wx) * wy;
      float w11 = wx * wy;
      size_t pp = (size_t)(v * PIX + ys * Ww + xs);
      const uint4* h16 = tf16 + pp;
      uint4 A = h16[0], B = h16[1];          // row ys, px xs/xs+1, ch0-15
      uint4 C = h16[Ww], D = h16[Ww + 1];    // row ys+1
      const unsigned char* t8 = tf8 + pp * 8;
      uint4 Tab = ld_u4_a8(t8);              // row ys: both tails in 16B
      uint4 Tcd = ld_u4_a8(t8 + Ww * 8);     // row ys+1
      acc16(A, w00, &acc[0]);
      acc16(B, w10, &acc[0]);
      acc16(C, w01, &acc[0]);
      acc16(D, w11, &acc[0]);
      acc8v(Tab.x, Tab.y, w00, &acc[16]);
      acc8v(Tab.z, Tab.w, w10, &acc[16]);
      acc8v(Tcd.x, Tcd.y, w01, &acc[16]);
      acc8v(Tcd.z, Tcd.w, w11, &acc[16]);
      zsum += iz;
      cnt++;
    }
  }

  float denom = fmaxf((float)cnt, 1.f);
  float invd = 1.f / denom;
  float z = zsum * invd;

  // h = pre_h[m] + (acc*invd) @ W_sp[0:24,:]  (W_sp: uniform scalar loads)
  float h[Cc];
  {
    const f32x4* ph4 = (const f32x4*)(pre_h + (size_t)m * Cc);
#pragma unroll
    for (int t = 0; t < 6; t++) {
      f32x4 v4 = ph4[t];
      h[4 * t + 0] = v4.x;
      h[4 * t + 1] = v4.y;
      h[4 * t + 2] = v4.z;
      h[4 * t + 3] = v4.w;
    }
  }
#pragma unroll
  for (int c = 0; c < Cc; c++) {
    float f = acc[c] * invd;
#pragma unroll
    for (int j = 0; j < Cc; j++) h[j] += f * W_sp[c * Cc + j];
  }

  // ---- fused finalize: zn channel + relu + heads, h never leaves regs ----
  float zn = (z > 0.f) ? (z - s_zmean) * s_izn : 0.f;
  float tsdf = b_t[0], occ = b_o[0];
#pragma unroll
  for (int j = 0; j < Cc; j++) {
    float hj = fmaxf(h[j] + zn * W_sp[24 * Cc + j], 0.f);
    tsdf += hj * W_t[j];
    occ += hj * W_o[j];
  }
  f32x2 o2 = {tsdf, occ};
  __builtin_nontemporal_store(o2, (f32x2*)out + n);
  __builtin_nontemporal_store((float)cnt, out + 2 * (size_t)Npts + n);
}

// ---------------- launch ---------------------------------------------------
extern "C" void kernel_launch(void* const* d_in, const int* in_sizes, int n_in,
                              void* d_out, int out_size, void* d_ws,
                              size_t ws_size, hipStream_t stream) {
  const float* pre_feat = (const float*)d_in[0];
  const int* pre_coords = (const int*)d_in[1];
  const float* feats = (const float*)d_in[2];
  const float* KRcam = (const float*)d_in[3];
  const float* vol_origin = (const float*)d_in[4];
  const float* w2ac = (const float*)d_in[5];
  const float* W_sp = (const float*)d_in[6];
  const float* b_sp = (const float*)d_in[7];
  const float* W_t = (const float*)d_in[8];
  const float* b_t = (const float*)d_in[9];
  const float* W_o = (const float*)d_in[10];
  const float* b_o = (const float*)d_in[11];

  float* out = (float*)d_out;
  char* ws = (char*)d_ws;
  double* red = (double*)(ws + OFF_RED);
  uint4* tf16 = (uint4*)(ws + OFF_TF16);
  uint2* tf8 = (uint2*)(ws + OFF_TF8);
  float* pre_h = (float*)(ws + OFF_PREH);

  prep_kernel<<<NB_TF + NB_GEMM + NB_Z, 256, 0, stream>>>(
      feats, pre_feat, W_sp, b_sp, pre_coords, KRcam, vol_origin, w2ac, tf16,
      tf8, pre_h, red, out);
  main_kernel<<<NB_Z, 256, 0, stream>>>(
      pre_coords, tf16, (const unsigned char*)tf8, KRcam, vol_origin, W_sp,
      W_t, b_t, W_o, b_o, pre_h, out, red);
}